// Round 1
// baseline (606.774 us; speedup 1.0000x reference)
//
#include <hip/hip_runtime.h>
#include <math.h>

#define N_TOPK 6000
#define POST_K 1000
#define WORDS 94            // ceil(6000/64)
#define SEL_CAP 8192
#define NMS_THRESH 0.7f

struct Hdr {
  unsigned int hist[256];
  unsigned int prefix;     // accumulated high bits of u* (radix select)
  unsigned int kth;        // remaining rank within current prefix
  unsigned int selCount;
  unsigned int pad;
};

// ---- shared decode (must match reference numerics; _rn blocks FMA contraction) ----
__device__ __forceinline__ void decode_one(int i,
    const int* __restrict__ bidx, const int* __restrict__ isz,
    const float* __restrict__ anc, const float* __restrict__ delta,
    float& x1, float& y1, float& x2, float& y2, bool& valid)
{
  float a0 = anc[(size_t)i*4+0], a1 = anc[(size_t)i*4+1];
  float a2 = anc[(size_t)i*4+2], a3 = anc[(size_t)i*4+3];
  float aw = __fsub_rn(a2, a0);
  float ah = __fsub_rn(a3, a1);
  float ax = __fadd_rn(a0, __fmul_rn(0.5f, aw));
  float ay = __fadd_rn(a1, __fmul_rn(0.5f, ah));
  float d0 = delta[(size_t)i*4+0], d1 = delta[(size_t)i*4+1];
  float d2 = delta[(size_t)i*4+2], d3 = delta[(size_t)i*4+3];
  float px = __fadd_rn(ax, __fmul_rn(d0, aw));
  float py = __fadd_rn(ay, __fmul_rn(d1, ah));
  float c2 = fminf(fmaxf(d2, -10.0f), 10.0f);
  float c3 = fminf(fmaxf(d3, -10.0f), 10.0f);
  // correctly-rounded f32 exp via double (central w.r.t. any 1-ulp reference exp)
  float pw = __fmul_rn(aw, (float)exp((double)c2));
  float ph = __fmul_rn(ah, (float)exp((double)c3));
  int b = bidx[i];
  float H = (float)isz[b*2+0];
  float W = (float)isz[b*2+1];
  float Wm = __fsub_rn(W, 1.0f);
  float Hm = __fsub_rn(H, 1.0f);
  float hw = __fmul_rn(0.5f, pw);
  float hh = __fmul_rn(0.5f, ph);
  x1 = fminf(fmaxf(__fsub_rn(px, hw), 0.0f), Wm);
  y1 = fminf(fmaxf(__fsub_rn(py, hh), 0.0f), Hm);
  x2 = fminf(fmaxf(__fadd_rn(px, hw), 0.0f), Wm);
  y2 = fminf(fmaxf(__fadd_rn(py, hh), 0.0f), Hm);
  valid = (__fsub_rn(x2, x1) >= 16.0f) && (__fsub_rn(y2, y1) >= 16.0f);
}

// ---- stage 1: decode + score -> monotone u32 key ----
__global__ void k_decode(const int* __restrict__ bidx, const int* __restrict__ isz,
                         const float* __restrict__ anc, const float* __restrict__ logits,
                         const float* __restrict__ delta, unsigned int* __restrict__ u, int N)
{
  for (int i = blockIdx.x*blockDim.x + threadIdx.x; i < N; i += gridDim.x*blockDim.x){
    float x1,y1,x2,y2; bool valid;
    decode_one(i, bidx, isz, anc, delta, x1, y1, x2, y2, valid);
    float s;
    if (valid){
      float x = logits[i];
      float e = (float)exp(-(double)x);           // exp-form sigmoid (XLA logistic expander)
      s = __fdiv_rn(1.0f, __fadd_rn(1.0f, e));
    } else {
      s = -__builtin_inff();
    }
    unsigned int b = __float_as_uint(s);
    u[i] = (b & 0x80000000u) ? ~b : (b | 0x80000000u);   // monotone: bigger u == bigger score
  }
}

// ---- radix select: 4x (hist + pick) ----
__global__ void k_init(Hdr* h){
  h->hist[threadIdx.x] = 0;
  if (threadIdx.x == 0){ h->prefix = 0; h->kth = N_TOPK; h->selCount = 0; }
}

__global__ void k_hist(const unsigned int* __restrict__ u, int N, Hdr* __restrict__ h, int shift){
  __shared__ unsigned int lh[256];
  if (threadIdx.x < 256) lh[threadIdx.x] = 0;
  __syncthreads();
  unsigned int pre = h->prefix;
  for (int i = blockIdx.x*blockDim.x + threadIdx.x; i < N; i += gridDim.x*blockDim.x){
    unsigned int v = u[i];
    bool ok = (shift == 24) || ((v >> (shift + 8)) == pre);
    if (ok) atomicAdd(&lh[(v >> shift) & 255u], 1u);
  }
  __syncthreads();
  if (threadIdx.x < 256){
    unsigned int c = lh[threadIdx.x];
    if (c) atomicAdd(&h->hist[threadIdx.x], c);
  }
}

__global__ void k_pick(Hdr* h){
  __shared__ unsigned int lh[256];
  lh[threadIdx.x] = h->hist[threadIdx.x];
  __syncthreads();
  if (threadIdx.x == 0){
    unsigned int k = h->kth, acc = 0, chosen = 0;
    for (int b = 255; b >= 0; --b){
      unsigned int c = lh[b];
      if (acc + c >= k){ chosen = (unsigned int)b; h->kth = k - acc; break; }
      acc += c;
    }
    h->prefix = (h->prefix << 8) | chosen;
  }
  __syncthreads();
  h->hist[threadIdx.x] = 0;   // ready for next pass
}

// ---- compact all u >= u* ; key64 = (u<<32) | ~idx  (desc sort => score desc, idx asc) ----
__global__ void k_compact(const unsigned int* __restrict__ u, int N,
                          Hdr* __restrict__ h, unsigned long long* __restrict__ sel){
  unsigned int ustar = h->prefix;
  for (int i = blockIdx.x*blockDim.x + threadIdx.x; i < N; i += gridDim.x*blockDim.x){
    unsigned int v = u[i];
    if (v >= ustar){
      unsigned int p = atomicAdd(&h->selCount, 1u);
      if (p < SEL_CAP)
        sel[p] = ((unsigned long long)v << 32)
               | (unsigned long long)(0xFFFFFFFFu - (unsigned int)i);
    }
  }
}

// ---- one-block bitonic sort, descending, 8192 u64 in LDS ----
__global__ void __launch_bounds__(1024) k_sort(unsigned long long* __restrict__ sel, Hdr* __restrict__ h){
  __shared__ unsigned long long sk[SEL_CAP];
  int n = (int)h->selCount; if (n > SEL_CAP) n = SEL_CAP;
  for (int v = threadIdx.x; v < SEL_CAP; v += 1024)
    sk[v] = (v < n) ? sel[v] : 0ULL;
  __syncthreads();
  for (int k = 2; k <= SEL_CAP; k <<= 1){
    for (int j = k >> 1; j > 0; j >>= 1){
      for (int v = (int)threadIdx.x; v < SEL_CAP/2; v += 1024){
        int i = ((v & ~(j-1)) << 1) | (v & (j-1));
        int p = i | j;
        unsigned long long a = sk[i], b = sk[p];
        bool desc = ((i & k) == 0);
        bool sw = desc ? (a < b) : (a > b);
        if (sw){ sk[i] = b; sk[p] = a; }
      }
      __syncthreads();
    }
  }
  for (int v = threadIdx.x; v < N_TOPK; v += 1024) sel[v] = sk[v];
}

// ---- gather + re-decode top-6000 ----
__global__ void k_gather(const unsigned long long* __restrict__ sel,
                         const int* __restrict__ bidx, const int* __restrict__ isz,
                         const float* __restrict__ anc, const float* __restrict__ delta,
                         float4* __restrict__ boxes, float* __restrict__ areas,
                         int* __restrict__ bidxv, int* __restrict__ validv)
{
  int k = blockIdx.x*blockDim.x + threadIdx.x;
  if (k >= N_TOPK) return;
  unsigned long long key = sel[k];
  unsigned int uv = (unsigned int)(key >> 32);
  int i = (int)(0xFFFFFFFFu - (unsigned int)(key & 0xFFFFFFFFull));
  float x1,y1,x2,y2; bool valid;
  decode_one(i, bidx, isz, anc, delta, x1, y1, x2, y2, valid);
  boxes[k] = make_float4(x1, y1, x2, y2);
  areas[k] = __fmul_rn(__fsub_rn(x2, x1), __fsub_rn(y2, y1));
  bidxv[k] = bidx[i];
  validv[k] = (uv >= 0x80000000u) ? 1 : 0;   // finite score
}

// ---- NMS suppression bitmask: 64x64 tiles ----
__global__ void __launch_bounds__(64) k_mask(const float4* __restrict__ boxes,
                                             const float* __restrict__ areas,
                                             unsigned long long* __restrict__ mask)
{
  __shared__ float4 cbox[64];
  __shared__ float carea[64];
  int t = threadIdx.x;
  int cb = blockIdx.x, rb = blockIdx.y;
  int col0 = cb * 64;
  int c = col0 + t;
  if (c < N_TOPK){ cbox[t] = boxes[c]; carea[t] = areas[c]; }
  __syncthreads();
  int r = rb * 64 + t;
  if (r >= N_TOPK) return;
  float4 rbx = boxes[r];
  float ra = areas[r];
  unsigned long long m = 0ULL;
  int jmax = N_TOPK - col0; if (jmax > 64) jmax = 64;
  for (int jj = 0; jj < jmax; ++jj){
    int cc = col0 + jj;
    if (cc <= r) continue;
    float4 cbx = cbox[jj];
    float ix1 = fmaxf(rbx.x, cbx.x);
    float iy1 = fmaxf(rbx.y, cbx.y);
    float ix2 = fminf(rbx.z, cbx.z);
    float iy2 = fminf(rbx.w, cbx.w);
    float iw = fmaxf(__fsub_rn(ix2, ix1), 0.0f);
    float ih = fmaxf(__fsub_rn(iy2, iy1), 0.0f);
    float inter = __fmul_rn(iw, ih);
    // ((a_i + a_j) - inter) + 1e-9  -- reference op order
    float denom = __fadd_rn(__fsub_rn(__fadd_rn(ra, carea[jj]), inter), 1e-9f);
    float iou = __fdiv_rn(inter, denom);
    if (iou > NMS_THRESH) m |= (1ULL << jj);
  }
  mask[(size_t)r * WORDS + cb] = m;
}

// ---- sequential greedy scan (1 wave) + output write, early-exit at 1000 kept ----
__global__ void __launch_bounds__(64) k_scan(const unsigned long long* __restrict__ mask,
                                             const int* __restrict__ validv,
                                             const float4* __restrict__ boxes,
                                             const int* __restrict__ bidxv,
                                             float* __restrict__ out)
{
  int lane = threadIdx.x;
  unsigned long long r0 = 0ULL, r1 = 0ULL;   // lane holds remv words lane and 64+lane
  __shared__ int keep[POST_K];
  int cnt = 0;
  // prefetch row 0
  unsigned long long pm0 = mask[lane];
  unsigned long long pm1 = (lane < 30) ? mask[64 + lane] : 0ULL;
  int pvld = validv[0];
  for (int i = 0; i < N_TOPK; ++i){
    unsigned long long c0 = pm0, c1 = pm1;
    int vld = pvld;
    if (i + 1 < N_TOPK){
      pm0 = mask[(size_t)(i+1) * WORDS + lane];
      pm1 = (lane < 30) ? mask[(size_t)(i+1) * WORDS + 64 + lane] : 0ULL;
      pvld = validv[i+1];
    }
    int w = i >> 6;
    unsigned long long word = (w < 64) ? __shfl(r0, w) : __shfl(r1, w - 64);
    bool alive = ((word >> (i & 63)) & 1ULL) == 0ULL;
    if (alive){
      r0 |= c0; r1 |= c1;                 // suppress forward (even if score -inf, per reference)
      if (vld){
        if (lane == 0) keep[cnt] = i;
        cnt++;
        if (cnt >= POST_K) break;         // later rows cannot affect first 1000 kept
      }
    }
  }
  __syncthreads();
  int kc = cnt > POST_K ? POST_K : cnt;
  for (int c = lane; c < POST_K; c += 64){
    float4 b; float bi;
    if (c < kc){
      int i = keep[c];
      b = boxes[i];
      bi = (float)bidxv[i];
    } else {
      b = make_float4(0.f, 0.f, 0.f, 0.f);
      bi = -1.0f;
    }
    out[c*4+0] = b.x; out[c*4+1] = b.y; out[c*4+2] = b.z; out[c*4+3] = b.w;
    out[POST_K*4 + c] = bi;
  }
}

extern "C" void kernel_launch(void* const* d_in, const int* in_sizes, int n_in,
                              void* d_out, int out_size, void* d_ws, size_t ws_size,
                              hipStream_t stream)
{
  const int*   bidx   = (const int*)d_in[0];
  const int*   isz    = (const int*)d_in[1];
  const float* anc    = (const float*)d_in[2];
  const float* logits = (const float*)d_in[3];
  const float* delta  = (const float*)d_in[4];
  const int N = in_sizes[0];

  char* ws = (char*)d_ws;
  size_t off = 0;
  unsigned int* u = (unsigned int*)(ws + off);      off += (size_t)N * 4;
  off = (off + 255) & ~(size_t)255;
  Hdr* h = (Hdr*)(ws + off);                        off += sizeof(Hdr);
  off = (off + 255) & ~(size_t)255;
  unsigned long long* sel = (unsigned long long*)(ws + off); off += (size_t)SEL_CAP * 8;
  float4* boxes = (float4*)(ws + off);              off += (size_t)N_TOPK * 16;
  float*  areas = (float*)(ws + off);               off += (size_t)N_TOPK * 4;
  int*    bidxv = (int*)(ws + off);                 off += (size_t)N_TOPK * 4;
  int*    validv= (int*)(ws + off);                 off += (size_t)N_TOPK * 4;
  off = (off + 255) & ~(size_t)255;
  unsigned long long* mask = (unsigned long long*)(ws + off); off += (size_t)N_TOPK * WORDS * 8;
  (void)ws_size; (void)n_in; (void)out_size;

  float* out = (float*)d_out;

  hipLaunchKernelGGL(k_decode, dim3(2048), dim3(256), 0, stream, bidx, isz, anc, logits, delta, u, N);
  hipLaunchKernelGGL(k_init,   dim3(1),    dim3(256), 0, stream, h);
  for (int shift = 24; shift >= 0; shift -= 8){
    hipLaunchKernelGGL(k_hist, dim3(1024), dim3(256), 0, stream, u, N, h, shift);
    hipLaunchKernelGGL(k_pick, dim3(1),    dim3(256), 0, stream, h);
  }
  hipLaunchKernelGGL(k_compact, dim3(2048), dim3(256), 0, stream, u, N, h, sel);
  hipLaunchKernelGGL(k_sort,    dim3(1),    dim3(1024), 0, stream, sel, h);
  hipLaunchKernelGGL(k_gather,  dim3((N_TOPK + 255)/256), dim3(256), 0, stream,
                     sel, bidx, isz, anc, delta, boxes, areas, bidxv, validv);
  hipLaunchKernelGGL(k_mask,    dim3(WORDS, WORDS), dim3(64), 0, stream, boxes, areas, mask);
  hipLaunchKernelGGL(k_scan,    dim3(1),    dim3(64), 0, stream, mask, validv, boxes, bidxv, out);
}

// Round 2
// 366.704 us; speedup vs baseline: 1.6547x; 1.6547x over previous
//
#include <hip/hip_runtime.h>
#include <math.h>

#define N_TOPK 6000
#define POST_K 1000
#define WORDS 94            // ceil(6000/64)
#define SEL_CAP 8192
#define NMS_THRESH 0.7f

struct Hdr {
  unsigned int hist[256];
  unsigned int prefix;     // accumulated high bits of u* (radix select)
  unsigned int kth;        // remaining rank within current prefix
  unsigned int selCount;
  unsigned int pad;
};

// ---- shared decode (must match reference numerics; _rn blocks FMA contraction) ----
__device__ __forceinline__ void decode_one(int i,
    const int* __restrict__ bidx, const int* __restrict__ isz,
    const float* __restrict__ anc, const float* __restrict__ delta,
    float& x1, float& y1, float& x2, float& y2, bool& valid)
{
  float a0 = anc[(size_t)i*4+0], a1 = anc[(size_t)i*4+1];
  float a2 = anc[(size_t)i*4+2], a3 = anc[(size_t)i*4+3];
  float aw = __fsub_rn(a2, a0);
  float ah = __fsub_rn(a3, a1);
  float ax = __fadd_rn(a0, __fmul_rn(0.5f, aw));
  float ay = __fadd_rn(a1, __fmul_rn(0.5f, ah));
  float d0 = delta[(size_t)i*4+0], d1 = delta[(size_t)i*4+1];
  float d2 = delta[(size_t)i*4+2], d3 = delta[(size_t)i*4+3];
  float px = __fadd_rn(ax, __fmul_rn(d0, aw));
  float py = __fadd_rn(ay, __fmul_rn(d1, ah));
  float c2 = fminf(fmaxf(d2, -10.0f), 10.0f);
  float c3 = fminf(fmaxf(d3, -10.0f), 10.0f);
  // correctly-rounded f32 exp via double (central w.r.t. any 1-ulp reference exp)
  float pw = __fmul_rn(aw, (float)exp((double)c2));
  float ph = __fmul_rn(ah, (float)exp((double)c3));
  int b = bidx[i];
  float H = (float)isz[b*2+0];
  float W = (float)isz[b*2+1];
  float Wm = __fsub_rn(W, 1.0f);
  float Hm = __fsub_rn(H, 1.0f);
  float hw = __fmul_rn(0.5f, pw);
  float hh = __fmul_rn(0.5f, ph);
  x1 = fminf(fmaxf(__fsub_rn(px, hw), 0.0f), Wm);
  y1 = fminf(fmaxf(__fsub_rn(py, hh), 0.0f), Hm);
  x2 = fminf(fmaxf(__fadd_rn(px, hw), 0.0f), Wm);
  y2 = fminf(fmaxf(__fadd_rn(py, hh), 0.0f), Hm);
  valid = (__fsub_rn(x2, x1) >= 16.0f) && (__fsub_rn(y2, y1) >= 16.0f);
}

// ---- stage 1: decode + score -> monotone u32 key ----
__global__ void k_decode(const int* __restrict__ bidx, const int* __restrict__ isz,
                         const float* __restrict__ anc, const float* __restrict__ logits,
                         const float* __restrict__ delta, unsigned int* __restrict__ u, int N)
{
  for (int i = blockIdx.x*blockDim.x + threadIdx.x; i < N; i += gridDim.x*blockDim.x){
    float x1,y1,x2,y2; bool valid;
    decode_one(i, bidx, isz, anc, delta, x1, y1, x2, y2, valid);
    float s;
    if (valid){
      float x = logits[i];
      float e = (float)exp(-(double)x);           // exp-form sigmoid (XLA logistic expander)
      s = __fdiv_rn(1.0f, __fadd_rn(1.0f, e));
    } else {
      s = -__builtin_inff();
    }
    unsigned int b = __float_as_uint(s);
    u[i] = (b & 0x80000000u) ? ~b : (b | 0x80000000u);   // monotone: bigger u == bigger score
  }
}

// ---- radix select: 4x (hist + pick) ----
__global__ void k_init(Hdr* h){
  h->hist[threadIdx.x] = 0;
  if (threadIdx.x == 0){ h->prefix = 0; h->kth = N_TOPK; h->selCount = 0; }
}

__global__ void k_hist(const unsigned int* __restrict__ u, int N, Hdr* __restrict__ h, int shift){
  __shared__ unsigned int lh[256];
  if (threadIdx.x < 256) lh[threadIdx.x] = 0;
  __syncthreads();
  unsigned int pre = h->prefix;
  for (int i = blockIdx.x*blockDim.x + threadIdx.x; i < N; i += gridDim.x*blockDim.x){
    unsigned int v = u[i];
    bool ok = (shift == 24) || ((v >> (shift + 8)) == pre);
    if (ok) atomicAdd(&lh[(v >> shift) & 255u], 1u);
  }
  __syncthreads();
  if (threadIdx.x < 256){
    unsigned int c = lh[threadIdx.x];
    if (c) atomicAdd(&h->hist[threadIdx.x], c);
  }
}

__global__ void k_pick(Hdr* h){
  __shared__ unsigned int lh[256];
  lh[threadIdx.x] = h->hist[threadIdx.x];
  __syncthreads();
  if (threadIdx.x == 0){
    unsigned int k = h->kth, acc = 0, chosen = 0;
    for (int b = 255; b >= 0; --b){
      unsigned int c = lh[b];
      if (acc + c >= k){ chosen = (unsigned int)b; h->kth = k - acc; break; }
      acc += c;
    }
    h->prefix = (h->prefix << 8) | chosen;
  }
  __syncthreads();
  h->hist[threadIdx.x] = 0;   // ready for next pass
}

// ---- compact all u >= u* ; key64 = (u<<32) | ~idx  (desc sort => score desc, idx asc) ----
__global__ void k_compact(const unsigned int* __restrict__ u, int N,
                          Hdr* __restrict__ h, unsigned long long* __restrict__ sel){
  unsigned int ustar = h->prefix;
  for (int i = blockIdx.x*blockDim.x + threadIdx.x; i < N; i += gridDim.x*blockDim.x){
    unsigned int v = u[i];
    if (v >= ustar){
      unsigned int p = atomicAdd(&h->selCount, 1u);
      if (p < SEL_CAP)
        sel[p] = ((unsigned long long)v << 32)
               | (unsigned long long)(0xFFFFFFFFu - (unsigned int)i);
    }
  }
}

// ---- one-block bitonic sort, descending, 8192 u64 in LDS ----
__global__ void __launch_bounds__(1024) k_sort(unsigned long long* __restrict__ sel, Hdr* __restrict__ h){
  __shared__ unsigned long long sk[SEL_CAP];
  int n = (int)h->selCount; if (n > SEL_CAP) n = SEL_CAP;
  for (int v = threadIdx.x; v < SEL_CAP; v += 1024)
    sk[v] = (v < n) ? sel[v] : 0ULL;
  __syncthreads();
  for (int k = 2; k <= SEL_CAP; k <<= 1){
    for (int j = k >> 1; j > 0; j >>= 1){
      for (int v = (int)threadIdx.x; v < SEL_CAP/2; v += 1024){
        int i = ((v & ~(j-1)) << 1) | (v & (j-1));
        int p = i | j;
        unsigned long long a = sk[i], b = sk[p];
        bool desc = ((i & k) == 0);
        bool sw = desc ? (a < b) : (a > b);
        if (sw){ sk[i] = b; sk[p] = a; }
      }
      __syncthreads();
    }
  }
  for (int v = threadIdx.x; v < N_TOPK; v += 1024) sel[v] = sk[v];
}

// ---- gather + re-decode top-6000 ----
__global__ void k_gather(const unsigned long long* __restrict__ sel,
                         const int* __restrict__ bidx, const int* __restrict__ isz,
                         const float* __restrict__ anc, const float* __restrict__ delta,
                         float4* __restrict__ boxes, float* __restrict__ areas,
                         int* __restrict__ bidxv, int* __restrict__ validv)
{
  int k = blockIdx.x*blockDim.x + threadIdx.x;
  if (k >= N_TOPK) return;
  unsigned long long key = sel[k];
  unsigned int uv = (unsigned int)(key >> 32);
  int i = (int)(0xFFFFFFFFu - (unsigned int)(key & 0xFFFFFFFFull));
  float x1,y1,x2,y2; bool valid;
  decode_one(i, bidx, isz, anc, delta, x1, y1, x2, y2, valid);
  boxes[k] = make_float4(x1, y1, x2, y2);
  areas[k] = __fmul_rn(__fsub_rn(x2, x1), __fsub_rn(y2, y1));
  bidxv[k] = bidx[i];
  validv[k] = (uv >= 0x80000000u) ? 1 : 0;   // finite score
}

// ---- NMS suppression bitmask: 64x64 tiles ----
__global__ void __launch_bounds__(64) k_mask(const float4* __restrict__ boxes,
                                             const float* __restrict__ areas,
                                             unsigned long long* __restrict__ mask)
{
  __shared__ float4 cbox[64];
  __shared__ float carea[64];
  int t = threadIdx.x;
  int cb = blockIdx.x, rb = blockIdx.y;
  int col0 = cb * 64;
  int c = col0 + t;
  if (c < N_TOPK){ cbox[t] = boxes[c]; carea[t] = areas[c]; }
  __syncthreads();
  int r = rb * 64 + t;
  if (r >= N_TOPK) return;
  float4 rbx = boxes[r];
  float ra = areas[r];
  unsigned long long m = 0ULL;
  int jmax = N_TOPK - col0; if (jmax > 64) jmax = 64;
  for (int jj = 0; jj < jmax; ++jj){
    int cc = col0 + jj;
    if (cc <= r) continue;
    float4 cbx = cbox[jj];
    float ix1 = fmaxf(rbx.x, cbx.x);
    float iy1 = fmaxf(rbx.y, cbx.y);
    float ix2 = fminf(rbx.z, cbx.z);
    float iy2 = fminf(rbx.w, cbx.w);
    float iw = fmaxf(__fsub_rn(ix2, ix1), 0.0f);
    float ih = fmaxf(__fsub_rn(iy2, iy1), 0.0f);
    float inter = __fmul_rn(iw, ih);
    // ((a_i + a_j) - inter) + 1e-9  -- reference op order
    float denom = __fadd_rn(__fsub_rn(__fadd_rn(ra, carea[jj]), inter), 1e-9f);
    float iou = __fdiv_rn(inter, denom);
    if (iou > NMS_THRESH) m |= (1ULL << jj);
  }
  mask[(size_t)r * WORDS + cb] = m;
}

// ---- chunked sequential greedy scan (1 wave): 64-row chunks.
//  The only serial chain is in-register bit logic; mask-row loads are
//  issued unconditionally (64/chunk) and pipelined by the compiler. ----
__global__ void __launch_bounds__(64) k_scan(const unsigned long long* __restrict__ mask,
                                             const int* __restrict__ validv,
                                             const float4* __restrict__ boxes,
                                             const int* __restrict__ bidxv,
                                             float* __restrict__ out)
{
  const int lane = threadIdx.x;
  __shared__ unsigned long long dtile[64];
  __shared__ int keep[POST_K];
  // lane l (<47) owns remv words 2l and 2l+1  (94 words total)
  unsigned long long rA = 0ULL, rB = 0ULL;
  int cnt = 0;
  const int NCHUNK = (N_TOPK + 63) / 64;   // 94
  for (int c = 0; c < NCHUNK; ++c){
    const int base = c * 64;
    const int nrows = (N_TOPK - base < 64) ? (N_TOPK - base) : 64;
    // prior-suppression word for this chunk's 64 rows = remv word c
    unsigned long long wA = __shfl(rA, c >> 1);
    unsigned long long wB = __shfl(rB, c >> 1);
    unsigned long long prevw = (c & 1) ? wB : wA;
    // diagonal tile: row base+lane, word c (intra-chunk suppression bits)
    int row = base + lane;
    unsigned long long diagv = (lane < nrows) ? mask[(size_t)row * WORDS + c] : 0ULL;
    dtile[lane] = diagv;
    unsigned long long vmask = __ballot(lane < nrows && validv[row < N_TOPK ? row : N_TOPK-1] != 0);
    // sequential resolve within chunk — pure register/LDS, replicated on all lanes
    unsigned long long s = prevw, alivebits = 0ULL;
    #pragma unroll
    for (int i = 0; i < 64; ++i){
      unsigned long long d = dtile[i];
      if (((s >> i) & 1ULL) == 0ULL){
        s |= d;
        alivebits |= (1ULL << i);
      }
    }
    unsigned long long keepbits = alivebits & vmask;
    if ((keepbits >> lane) & 1ULL){
      int pos = cnt + __popcll(keepbits & ((1ULL << lane) - 1ULL));
      if (pos < POST_K) keep[pos] = base + lane;
    }
    cnt += (int)__popcll(keepbits);
    if (cnt >= POST_K || c + 1 == NCHUNK) break;  // later rows can't change first 1000 kept
    // OR alive rows' full masks into distributed remv.
    // All 64 rows loaded unconditionally (independent, pipelined); AND with alive bit.
    if (lane < 47){
      const char* mb = (const char*)mask;
      size_t lo = (size_t)lane * 16;
      #pragma unroll
      for (int i = 0; i < 64; ++i){
        int rr = base + i;                      // rr <= 5951 here (c <= 92)
        ulonglong2 v = *(const ulonglong2*)(mb + (size_t)rr * (WORDS * 8) + lo);
        unsigned long long selm = 0ULL - ((alivebits >> i) & 1ULL);
        rA |= v.x & selm;
        rB |= v.y & selm;
      }
    }
  }
  __syncthreads();
  int kc = cnt > POST_K ? POST_K : cnt;
  for (int cc = lane; cc < POST_K; cc += 64){
    float4 b; float bi;
    if (cc < kc){
      int i = keep[cc];
      b = boxes[i];
      bi = (float)bidxv[i];
    } else {
      b = make_float4(0.f, 0.f, 0.f, 0.f);
      bi = -1.0f;
    }
    out[cc*4+0] = b.x; out[cc*4+1] = b.y; out[cc*4+2] = b.z; out[cc*4+3] = b.w;
    out[POST_K*4 + cc] = bi;
  }
}

extern "C" void kernel_launch(void* const* d_in, const int* in_sizes, int n_in,
                              void* d_out, int out_size, void* d_ws, size_t ws_size,
                              hipStream_t stream)
{
  const int*   bidx   = (const int*)d_in[0];
  const int*   isz    = (const int*)d_in[1];
  const float* anc    = (const float*)d_in[2];
  const float* logits = (const float*)d_in[3];
  const float* delta  = (const float*)d_in[4];
  const int N = in_sizes[0];

  char* ws = (char*)d_ws;
  size_t off = 0;
  unsigned int* u = (unsigned int*)(ws + off);      off += (size_t)N * 4;
  off = (off + 255) & ~(size_t)255;
  Hdr* h = (Hdr*)(ws + off);                        off += sizeof(Hdr);
  off = (off + 255) & ~(size_t)255;
  unsigned long long* sel = (unsigned long long*)(ws + off); off += (size_t)SEL_CAP * 8;
  float4* boxes = (float4*)(ws + off);              off += (size_t)N_TOPK * 16;
  float*  areas = (float*)(ws + off);               off += (size_t)N_TOPK * 4;
  int*    bidxv = (int*)(ws + off);                 off += (size_t)N_TOPK * 4;
  int*    validv= (int*)(ws + off);                 off += (size_t)N_TOPK * 4;
  off = (off + 255) & ~(size_t)255;
  unsigned long long* mask = (unsigned long long*)(ws + off); off += (size_t)N_TOPK * WORDS * 8;
  (void)ws_size; (void)n_in; (void)out_size;

  float* out = (float*)d_out;

  hipLaunchKernelGGL(k_decode, dim3(2048), dim3(256), 0, stream, bidx, isz, anc, logits, delta, u, N);
  hipLaunchKernelGGL(k_init,   dim3(1),    dim3(256), 0, stream, h);
  for (int shift = 24; shift >= 0; shift -= 8){
    hipLaunchKernelGGL(k_hist, dim3(1024), dim3(256), 0, stream, u, N, h, shift);
    hipLaunchKernelGGL(k_pick, dim3(1),    dim3(256), 0, stream, h);
  }
  hipLaunchKernelGGL(k_compact, dim3(2048), dim3(256), 0, stream, u, N, h, sel);
  hipLaunchKernelGGL(k_sort,    dim3(1),    dim3(1024), 0, stream, sel, h);
  hipLaunchKernelGGL(k_gather,  dim3((N_TOPK + 255)/256), dim3(256), 0, stream,
                     sel, bidx, isz, anc, delta, boxes, areas, bidxv, validv);
  hipLaunchKernelGGL(k_mask,    dim3(WORDS, WORDS), dim3(64), 0, stream, boxes, areas, mask);
  hipLaunchKernelGGL(k_scan,    dim3(1),    dim3(64), 0, stream, mask, validv, boxes, bidxv, out);
}

// Round 3
// 344.236 us; speedup vs baseline: 1.7627x; 1.0653x over previous
//
#include <hip/hip_runtime.h>
#include <math.h>

#define N_TOPK 6000
#define POST_K 1000
#define WORDS 94            // ceil(6000/64)
#define SEL_CAP 8192
#define NMS_THRESH 0.7f

struct Hdr {
  unsigned int hist[256];
  unsigned int prefix;     // accumulated high bits of u* (radix select)
  unsigned int kth;        // remaining rank within current prefix
  unsigned int selCount;
  unsigned int pad;
};

// ---- shared decode (must match reference numerics; _rn blocks FMA contraction) ----
__device__ __forceinline__ void decode_one(int i,
    const int* __restrict__ bidx, const int* __restrict__ isz,
    const float* __restrict__ anc, const float* __restrict__ delta,
    float& x1, float& y1, float& x2, float& y2, bool& valid)
{
  float a0 = anc[(size_t)i*4+0], a1 = anc[(size_t)i*4+1];
  float a2 = anc[(size_t)i*4+2], a3 = anc[(size_t)i*4+3];
  float aw = __fsub_rn(a2, a0);
  float ah = __fsub_rn(a3, a1);
  float ax = __fadd_rn(a0, __fmul_rn(0.5f, aw));
  float ay = __fadd_rn(a1, __fmul_rn(0.5f, ah));
  float d0 = delta[(size_t)i*4+0], d1 = delta[(size_t)i*4+1];
  float d2 = delta[(size_t)i*4+2], d3 = delta[(size_t)i*4+3];
  float px = __fadd_rn(ax, __fmul_rn(d0, aw));
  float py = __fadd_rn(ay, __fmul_rn(d1, ah));
  float c2 = fminf(fmaxf(d2, -10.0f), 10.0f);
  float c3 = fminf(fmaxf(d3, -10.0f), 10.0f);
  // correctly-rounded f32 exp via double (central w.r.t. any 1-ulp reference exp)
  float pw = __fmul_rn(aw, (float)exp((double)c2));
  float ph = __fmul_rn(ah, (float)exp((double)c3));
  int b = bidx[i];
  float H = (float)isz[b*2+0];
  float W = (float)isz[b*2+1];
  float Wm = __fsub_rn(W, 1.0f);
  float Hm = __fsub_rn(H, 1.0f);
  float hw = __fmul_rn(0.5f, pw);
  float hh = __fmul_rn(0.5f, ph);
  x1 = fminf(fmaxf(__fsub_rn(px, hw), 0.0f), Wm);
  y1 = fminf(fmaxf(__fsub_rn(py, hh), 0.0f), Hm);
  x2 = fminf(fmaxf(__fadd_rn(px, hw), 0.0f), Wm);
  y2 = fminf(fmaxf(__fadd_rn(py, hh), 0.0f), Hm);
  valid = (__fsub_rn(x2, x1) >= 16.0f) && (__fsub_rn(y2, y1) >= 16.0f);
}

// ---- stage 1: decode + score -> monotone u32 key; fused top-8-bit histogram ----
__global__ void k_decode(const int* __restrict__ bidx, const int* __restrict__ isz,
                         const float* __restrict__ anc, const float* __restrict__ logits,
                         const float* __restrict__ delta, unsigned int* __restrict__ u, int N,
                         Hdr* __restrict__ h)
{
  __shared__ unsigned int lh[256];
  lh[threadIdx.x] = 0;
  __syncthreads();
  for (int i = blockIdx.x*blockDim.x + threadIdx.x; i < N; i += gridDim.x*blockDim.x){
    float x1,y1,x2,y2; bool valid;
    decode_one(i, bidx, isz, anc, delta, x1, y1, x2, y2, valid);
    float s;
    if (valid){
      float x = logits[i];
      float e = (float)exp(-(double)x);           // exp-form sigmoid (XLA logistic expander)
      s = __fdiv_rn(1.0f, __fadd_rn(1.0f, e));
    } else {
      s = -__builtin_inff();
    }
    unsigned int b = __float_as_uint(s);
    unsigned int key = (b & 0x80000000u) ? ~b : (b | 0x80000000u);
    u[i] = key;
    atomicAdd(&lh[key >> 24], 1u);
  }
  __syncthreads();
  unsigned int c = lh[threadIdx.x];
  if (c) atomicAdd(&h->hist[threadIdx.x], c);
}

// ---- radix select ----
__global__ void k_init(Hdr* h){
  h->hist[threadIdx.x] = 0;
  if (threadIdx.x == 0){ h->prefix = 0; h->kth = N_TOPK; h->selCount = 0; }
}

__global__ void k_hist(const unsigned int* __restrict__ u, int N, Hdr* __restrict__ h, int shift){
  __shared__ unsigned int lh[256];
  if (threadIdx.x < 256) lh[threadIdx.x] = 0;
  __syncthreads();
  unsigned int pre = h->prefix;
  for (int i = blockIdx.x*blockDim.x + threadIdx.x; i < N; i += gridDim.x*blockDim.x){
    unsigned int v = u[i];
    bool ok = ((v >> (shift + 8)) == pre);
    if (ok) atomicAdd(&lh[(v >> shift) & 255u], 1u);
  }
  __syncthreads();
  if (threadIdx.x < 256){
    unsigned int c = lh[threadIdx.x];
    if (c) atomicAdd(&h->hist[threadIdx.x], c);
  }
}

__global__ void k_pick(Hdr* h){
  __shared__ unsigned int lh[256];
  lh[threadIdx.x] = h->hist[threadIdx.x];
  __syncthreads();
  if (threadIdx.x == 0){
    unsigned int k = h->kth, acc = 0, chosen = 0;
    for (int b = 255; b >= 0; --b){
      unsigned int c = lh[b];
      if (acc + c >= k){ chosen = (unsigned int)b; h->kth = k - acc; break; }
      acc += c;
    }
    h->prefix = (h->prefix << 8) | chosen;
  }
  __syncthreads();
  h->hist[threadIdx.x] = 0;   // ready for next pass
}

// ---- compact all u >= u* ; key64 = (u<<32) | ~idx  (desc sort => score desc, idx asc) ----
__global__ void k_compact(const unsigned int* __restrict__ u, int N,
                          Hdr* __restrict__ h, unsigned long long* __restrict__ sel){
  unsigned int ustar = h->prefix;
  for (int i = blockIdx.x*blockDim.x + threadIdx.x; i < N; i += gridDim.x*blockDim.x){
    unsigned int v = u[i];
    if (v >= ustar){
      unsigned int p = atomicAdd(&h->selCount, 1u);
      if (p < SEL_CAP)
        sel[p] = ((unsigned long long)v << 32)
               | (unsigned long long)(0xFFFFFFFFu - (unsigned int)i);
    }
  }
}

// ---- register bitonic sort, descending, 8192 u64, 8 elems/thread ----
// stages j<8 in registers (templated J: static indices), j=8..256 via shfl_xor
// (lane distance j/8 <= 32, intra-wave), j>=512 via LDS (10 stages only).
template<int J>
__device__ __forceinline__ void reg_stage(unsigned long long (&v)[8], int t, int k){
  #pragma unroll
  for (int r = 0; r < 8; ++r){
    if ((r & J) == 0){
      const int rp = r | J;
      int e = t*8 + r;
      bool desc = (e & k) == 0;
      unsigned long long a = v[r], b = v[rp];
      bool sw = desc ? (a < b) : (a > b);
      if (sw){ v[r] = b; v[rp] = a; }
    }
  }
}

__global__ void __launch_bounds__(1024) k_sort(unsigned long long* __restrict__ sel,
                                               Hdr* __restrict__ h){
  __shared__ unsigned long long sk[SEL_CAP];
  const int t = threadIdx.x;
  int n = (int)h->selCount; if (n > SEL_CAP) n = SEL_CAP;
  unsigned long long v[8];
  #pragma unroll
  for (int r = 0; r < 8; ++r){
    int e = t*8 + r;
    v[r] = (e < n) ? sel[e] : 0ULL;
  }
  #pragma unroll 1
  for (int k = 2; k <= SEL_CAP; k <<= 1){
    // LDS stages (j >= 512)
    #pragma unroll 1
    for (int j = k >> 1; j >= 512; j >>= 1){
      __syncthreads();                       // WAR: prior stage's reads done
      #pragma unroll
      for (int r = 0; r < 8; ++r) sk[t*8 + r] = v[r];
      __syncthreads();
      #pragma unroll
      for (int r = 0; r < 8; ++r){
        int e = t*8 + r;
        unsigned long long b = sk[e ^ j];
        bool iLower = (e & j) == 0;
        bool desc = (e & k) == 0;
        unsigned long long a = v[r];
        v[r] = (desc == iLower) ? (a > b ? a : b) : (a < b ? a : b);
      }
    }
    // shfl stages (8 <= j <= 256)
    int jstart = (k >> 1) < 256 ? (k >> 1) : 256;
    #pragma unroll 1
    for (int j = jstart; j >= 8; j >>= 1){
      int dist = j >> 3;
      #pragma unroll
      for (int r = 0; r < 8; ++r){
        int e = t*8 + r;
        unsigned long long b = __shfl_xor(v[r], dist, 64);
        bool iLower = (e & j) == 0;
        bool desc = (e & k) == 0;
        unsigned long long a = v[r];
        v[r] = (desc == iLower) ? (a > b ? a : b) : (a < b ? a : b);
      }
    }
    // register stages (j = 4,2,1)
    if (k > 4) reg_stage<4>(v, t, k);
    if (k > 2) reg_stage<2>(v, t, k);
    reg_stage<1>(v, t, k);
  }
  #pragma unroll
  for (int r = 0; r < 8; ++r){
    int e = t*8 + r;
    if (e < N_TOPK) sel[e] = v[r];
  }
}

// ---- gather + re-decode top-6000 ----
__global__ void k_gather(const unsigned long long* __restrict__ sel,
                         const int* __restrict__ bidx, const int* __restrict__ isz,
                         const float* __restrict__ anc, const float* __restrict__ delta,
                         float4* __restrict__ boxes, float* __restrict__ areas,
                         int* __restrict__ bidxv, int* __restrict__ validv)
{
  int k = blockIdx.x*blockDim.x + threadIdx.x;
  if (k >= N_TOPK) return;
  unsigned long long key = sel[k];
  unsigned int uv = (unsigned int)(key >> 32);
  int i = (int)(0xFFFFFFFFu - (unsigned int)(key & 0xFFFFFFFFull));
  float x1,y1,x2,y2; bool valid;
  decode_one(i, bidx, isz, anc, delta, x1, y1, x2, y2, valid);
  boxes[k] = make_float4(x1, y1, x2, y2);
  areas[k] = __fmul_rn(__fsub_rn(x2, x1), __fsub_rn(y2, y1));
  bidxv[k] = bidx[i];
  validv[k] = (uv >= 0x80000000u) ? 1 : 0;   // finite score
}

// ---- NMS suppression bitmask: 64x64 tiles ----
__global__ void __launch_bounds__(64) k_mask(const float4* __restrict__ boxes,
                                             const float* __restrict__ areas,
                                             unsigned long long* __restrict__ mask)
{
  __shared__ float4 cbox[64];
  __shared__ float carea[64];
  int t = threadIdx.x;
  int cb = blockIdx.x, rb = blockIdx.y;
  int col0 = cb * 64;
  int c = col0 + t;
  if (c < N_TOPK){ cbox[t] = boxes[c]; carea[t] = areas[c]; }
  __syncthreads();
  int r = rb * 64 + t;
  if (r >= N_TOPK) return;
  float4 rbx = boxes[r];
  float ra = areas[r];
  unsigned long long m = 0ULL;
  int jmax = N_TOPK - col0; if (jmax > 64) jmax = 64;
  for (int jj = 0; jj < jmax; ++jj){
    int cc = col0 + jj;
    if (cc <= r) continue;
    float4 cbx = cbox[jj];
    float ix1 = fmaxf(rbx.x, cbx.x);
    float iy1 = fmaxf(rbx.y, cbx.y);
    float ix2 = fminf(rbx.z, cbx.z);
    float iy2 = fminf(rbx.w, cbx.w);
    float iw = fmaxf(__fsub_rn(ix2, ix1), 0.0f);
    float ih = fmaxf(__fsub_rn(iy2, iy1), 0.0f);
    float inter = __fmul_rn(iw, ih);
    float denom = __fadd_rn(__fsub_rn(__fadd_rn(ra, carea[jj]), inter), 1e-9f);
    float iou = __fdiv_rn(inter, denom);
    if (iou > NMS_THRESH) m |= (1ULL << jj);
  }
  mask[(size_t)r * WORDS + cb] = m;
}

// ---- chunked greedy scan, 4 waves (256 thr) ----
//  serial chain: 64-step register/shfl resolve per chunk; mask-row OR loads are
//  split 16 rows/wave (4x memory parallelism) into LDS remv via atomicOr;
//  next chunk's diagonal+valid prefetched before the OR loads.
__global__ void __launch_bounds__(256) k_scan(const unsigned long long* __restrict__ mask,
                                              const int* __restrict__ validv,
                                              const float4* __restrict__ boxes,
                                              const int* __restrict__ bidxv,
                                              float* __restrict__ out)
{
  const int t = threadIdx.x;
  const int lane = t & 63;
  const int wv = t >> 6;
  __shared__ unsigned long long remv[WORDS];
  __shared__ int keep[POST_K];
  for (int w = t; w < WORDS; w += 256) remv[w] = 0ULL;
  __syncthreads();

  const int NCHUNK = (N_TOPK + 63) / 64;   // 94
  int cnt = 0;
  // prefetch chunk 0 diagonal + valid
  unsigned long long dvP = (lane < N_TOPK) ? mask[(size_t)lane * WORDS + 0] : 0ULL;
  bool vbP = (lane < N_TOPK) ? (validv[lane] != 0) : false;

  for (int c = 0; c < NCHUNK; ++c){
    const int base = c * 64;
    const int nrows = (N_TOPK - base < 64) ? (N_TOPK - base) : 64;
    unsigned long long dv = (lane < nrows) ? dvP : 0ULL;
    bool vb = (lane < nrows) ? vbP : false;
    unsigned long long prevw = remv[c];
    unsigned long long vmask = __ballot(vb);
    // 64-step sequential resolve, replicated on all waves (register shfl chain)
    unsigned long long s = prevw, alive = 0ULL;
    #pragma unroll
    for (int i = 0; i < 64; ++i){
      unsigned long long d = __shfl(dv, i);
      if (((s >> i) & 1ULL) == 0ULL){
        s |= d;
        alive |= (1ULL << i);
      }
    }
    unsigned long long keepb = alive & vmask;
    if (wv == 0 && ((keepb >> lane) & 1ULL)){
      int pos = cnt + __popcll(keepb & ((1ULL << lane) - 1ULL));
      if (pos < POST_K) keep[pos] = base + lane;
    }
    cnt += (int)__popcll(keepb);
    if (cnt >= POST_K || c + 1 == NCHUNK) break;   // uniform across all threads
    // prefetch chunk c+1 diagonal + valid (overlaps with OR loads below)
    {
      int nb = base + 64;
      int nr2 = N_TOPK - nb; if (nr2 > 64) nr2 = 64;
      bool in2 = lane < nr2;
      int row2 = nb + lane;
      dvP = in2 ? mask[(size_t)row2 * WORDS + (c + 1)] : 0ULL;
      vbP = in2 ? (validv[row2] != 0) : false;
    }
    // OR phase: wave wv handles rows [wv*16, wv*16+16); lane<47 owns words 2l,2l+1
    if (lane < 47){
      unsigned long long a0 = 0ULL, a1 = 0ULL;
      const char* mb = (const char*)mask;
      const size_t lo = (size_t)lane * 16;
      #pragma unroll
      for (int i = 0; i < 16; ++i){
        int rr = base + wv*16 + i;
        unsigned long long selm = 0ULL - ((alive >> (wv*16 + i)) & 1ULL);
        ulonglong2 vv = *(const ulonglong2*)(mb + (size_t)rr * (WORDS * 8) + lo);
        a0 |= vv.x & selm;
        a1 |= vv.y & selm;
      }
      if (a0) atomicOr(&remv[2*lane],     a0);
      if (a1) atomicOr(&remv[2*lane + 1], a1);
    }
    __syncthreads();
  }
  __syncthreads();
  int kc = cnt > POST_K ? POST_K : cnt;
  for (int cc = t; cc < POST_K; cc += 256){
    float4 b; float bi;
    if (cc < kc){
      int i = keep[cc];
      b = boxes[i];
      bi = (float)bidxv[i];
    } else {
      b = make_float4(0.f, 0.f, 0.f, 0.f);
      bi = -1.0f;
    }
    out[cc*4+0] = b.x; out[cc*4+1] = b.y; out[cc*4+2] = b.z; out[cc*4+3] = b.w;
    out[POST_K*4 + cc] = bi;
  }
}

extern "C" void kernel_launch(void* const* d_in, const int* in_sizes, int n_in,
                              void* d_out, int out_size, void* d_ws, size_t ws_size,
                              hipStream_t stream)
{
  const int*   bidx   = (const int*)d_in[0];
  const int*   isz    = (const int*)d_in[1];
  const float* anc    = (const float*)d_in[2];
  const float* logits = (const float*)d_in[3];
  const float* delta  = (const float*)d_in[4];
  const int N = in_sizes[0];

  char* ws = (char*)d_ws;
  size_t off = 0;
  unsigned int* u = (unsigned int*)(ws + off);      off += (size_t)N * 4;
  off = (off + 255) & ~(size_t)255;
  Hdr* h = (Hdr*)(ws + off);                        off += sizeof(Hdr);
  off = (off + 255) & ~(size_t)255;
  unsigned long long* sel = (unsigned long long*)(ws + off); off += (size_t)SEL_CAP * 8;
  float4* boxes = (float4*)(ws + off);              off += (size_t)N_TOPK * 16;
  float*  areas = (float*)(ws + off);               off += (size_t)N_TOPK * 4;
  int*    bidxv = (int*)(ws + off);                 off += (size_t)N_TOPK * 4;
  int*    validv= (int*)(ws + off);                 off += (size_t)N_TOPK * 4;
  off = (off + 255) & ~(size_t)255;
  unsigned long long* mask = (unsigned long long*)(ws + off); off += (size_t)N_TOPK * WORDS * 8;
  (void)ws_size; (void)n_in; (void)out_size;

  float* out = (float*)d_out;

  hipLaunchKernelGGL(k_init,   dim3(1),    dim3(256), 0, stream, h);
  hipLaunchKernelGGL(k_decode, dim3(2048), dim3(256), 0, stream, bidx, isz, anc, logits, delta, u, N, h);
  hipLaunchKernelGGL(k_pick,   dim3(1),    dim3(256), 0, stream, h);
  for (int shift = 16; shift >= 0; shift -= 8){
    hipLaunchKernelGGL(k_hist, dim3(1024), dim3(256), 0, stream, u, N, h, shift);
    hipLaunchKernelGGL(k_pick, dim3(1),    dim3(256), 0, stream, h);
  }
  hipLaunchKernelGGL(k_compact, dim3(2048), dim3(256), 0, stream, u, N, h, sel);
  hipLaunchKernelGGL(k_sort,    dim3(1),    dim3(1024), 0, stream, sel, h);
  hipLaunchKernelGGL(k_gather,  dim3((N_TOPK + 255)/256), dim3(256), 0, stream,
                     sel, bidx, isz, anc, delta, boxes, areas, bidxv, validv);
  hipLaunchKernelGGL(k_mask,    dim3(WORDS, WORDS), dim3(64), 0, stream, boxes, areas, mask);
  hipLaunchKernelGGL(k_scan,    dim3(1),    dim3(256), 0, stream, mask, validv, boxes, bidxv, out);
}

// Round 4
// 293.927 us; speedup vs baseline: 2.0644x; 1.1712x over previous
//
#include <hip/hip_runtime.h>
#include <math.h>

#define N_TOPK 6000
#define POST_K 1000
#define WORDS 94            // ceil(6000/64)
#define SEL_CAP 8192
#define RANK_JT 1024
#define NMS_THRESH 0.7f

struct Hdr {
  unsigned int hist[256];
  unsigned int prefix;     // accumulated high bits of u* (radix select)
  unsigned int kth;        // remaining rank within current prefix
  unsigned int selCount;
  unsigned int pad;
};

// ---- shared decode (must match reference numerics; _rn blocks FMA contraction) ----
__device__ __forceinline__ void decode_one(int i,
    const int* __restrict__ bidx, const int* __restrict__ isz,
    const float* __restrict__ anc, const float* __restrict__ delta,
    float& x1, float& y1, float& x2, float& y2, bool& valid)
{
  float a0 = anc[(size_t)i*4+0], a1 = anc[(size_t)i*4+1];
  float a2 = anc[(size_t)i*4+2], a3 = anc[(size_t)i*4+3];
  float aw = __fsub_rn(a2, a0);
  float ah = __fsub_rn(a3, a1);
  float ax = __fadd_rn(a0, __fmul_rn(0.5f, aw));
  float ay = __fadd_rn(a1, __fmul_rn(0.5f, ah));
  float d0 = delta[(size_t)i*4+0], d1 = delta[(size_t)i*4+1];
  float d2 = delta[(size_t)i*4+2], d3 = delta[(size_t)i*4+3];
  float px = __fadd_rn(ax, __fmul_rn(d0, aw));
  float py = __fadd_rn(ay, __fmul_rn(d1, ah));
  float c2 = fminf(fmaxf(d2, -10.0f), 10.0f);
  float c3 = fminf(fmaxf(d3, -10.0f), 10.0f);
  // correctly-rounded f32 exp via double (central w.r.t. any 1-ulp reference exp)
  float pw = __fmul_rn(aw, (float)exp((double)c2));
  float ph = __fmul_rn(ah, (float)exp((double)c3));
  int b = bidx[i];
  float H = (float)isz[b*2+0];
  float W = (float)isz[b*2+1];
  float Wm = __fsub_rn(W, 1.0f);
  float Hm = __fsub_rn(H, 1.0f);
  float hw = __fmul_rn(0.5f, pw);
  float hh = __fmul_rn(0.5f, ph);
  x1 = fminf(fmaxf(__fsub_rn(px, hw), 0.0f), Wm);
  y1 = fminf(fmaxf(__fsub_rn(py, hh), 0.0f), Hm);
  x2 = fminf(fmaxf(__fadd_rn(px, hw), 0.0f), Wm);
  y2 = fminf(fmaxf(__fadd_rn(py, hh), 0.0f), Hm);
  valid = (__fsub_rn(x2, x1) >= 16.0f) && (__fsub_rn(y2, y1) >= 16.0f);
}

// ---- stage 1: decode + score -> monotone u32 key; fused top-8-bit histogram ----
__global__ void k_decode(const int* __restrict__ bidx, const int* __restrict__ isz,
                         const float* __restrict__ anc, const float* __restrict__ logits,
                         const float* __restrict__ delta, unsigned int* __restrict__ u, int N,
                         Hdr* __restrict__ h)
{
  __shared__ unsigned int lh[256];
  lh[threadIdx.x] = 0;
  __syncthreads();
  for (int i = blockIdx.x*blockDim.x + threadIdx.x; i < N; i += gridDim.x*blockDim.x){
    float x1,y1,x2,y2; bool valid;
    decode_one(i, bidx, isz, anc, delta, x1, y1, x2, y2, valid);
    float s;
    if (valid){
      float x = logits[i];
      float e = (float)exp(-(double)x);           // exp-form sigmoid (XLA logistic expander)
      s = __fdiv_rn(1.0f, __fadd_rn(1.0f, e));
    } else {
      s = -__builtin_inff();
    }
    unsigned int b = __float_as_uint(s);
    unsigned int key = (b & 0x80000000u) ? ~b : (b | 0x80000000u);
    u[i] = key;
    atomicAdd(&lh[key >> 24], 1u);
  }
  __syncthreads();
  unsigned int c = lh[threadIdx.x];
  if (c) atomicAdd(&h->hist[threadIdx.x], c);
}

// ---- radix select ----
__global__ void k_init(Hdr* h, unsigned int* rank){
  h->hist[threadIdx.x] = 0;
  for (int i = threadIdx.x; i < SEL_CAP; i += 256) rank[i] = 0;
  if (threadIdx.x == 0){ h->prefix = 0; h->kth = N_TOPK; h->selCount = 0; }
}

__global__ void k_hist(const unsigned int* __restrict__ u, int N, Hdr* __restrict__ h, int shift){
  __shared__ unsigned int lh[256];
  if (threadIdx.x < 256) lh[threadIdx.x] = 0;
  __syncthreads();
  unsigned int pre = h->prefix;
  for (int i = blockIdx.x*blockDim.x + threadIdx.x; i < N; i += gridDim.x*blockDim.x){
    unsigned int v = u[i];
    bool ok = ((v >> (shift + 8)) == pre);
    if (ok) atomicAdd(&lh[(v >> shift) & 255u], 1u);
  }
  __syncthreads();
  if (threadIdx.x < 256){
    unsigned int c = lh[threadIdx.x];
    if (c) atomicAdd(&h->hist[threadIdx.x], c);
  }
}

__global__ void k_pick(Hdr* h){
  __shared__ unsigned int lh[256];
  lh[threadIdx.x] = h->hist[threadIdx.x];
  __syncthreads();
  if (threadIdx.x == 0){
    unsigned int k = h->kth, acc = 0, chosen = 0;
    for (int b = 255; b >= 0; --b){
      unsigned int c = lh[b];
      if (acc + c >= k){ chosen = (unsigned int)b; h->kth = k - acc; break; }
      acc += c;
    }
    h->prefix = (h->prefix << 8) | chosen;
  }
  __syncthreads();
  h->hist[threadIdx.x] = 0;   // ready for next pass
}

// ---- compact all u >= u* ; key64 = (u<<32) | ~idx  (desc order => score desc, idx asc) ----
__global__ void k_compact(const unsigned int* __restrict__ u, int N,
                          Hdr* __restrict__ h, unsigned long long* __restrict__ sel){
  unsigned int ustar = h->prefix;
  for (int i = blockIdx.x*blockDim.x + threadIdx.x; i < N; i += gridDim.x*blockDim.x){
    unsigned int v = u[i];
    if (v >= ustar){
      unsigned int p = atomicAdd(&h->selCount, 1u);
      if (p < SEL_CAP)
        sel[p] = ((unsigned long long)v << 32)
               | (unsigned long long)(0xFFFFFFFFu - (unsigned int)i);
    }
  }
}

// ---- rank instead of sort: rank_i = #{j : key_j > key_i} (keys unique).
//  2D grid: 32 i-blocks x 8 j-tiles; j-tile in LDS (broadcast reads). ----
__global__ void __launch_bounds__(256) k_rank(const unsigned long long* __restrict__ sel,
                                              const Hdr* __restrict__ h,
                                              unsigned int* __restrict__ rank){
  __shared__ unsigned long long tile[RANK_JT];
  int n = (int)h->selCount; if (n > SEL_CAP) n = SEL_CAP;
  int i = blockIdx.x*256 + threadIdx.x;
  unsigned long long ki = (i < n) ? sel[i] : 0ULL;
  int j0 = blockIdx.y * RANK_JT;
  for (int jj = threadIdx.x; jj < RANK_JT; jj += 256)
    tile[jj] = (j0 + jj < n) ? sel[j0 + jj] : 0ULL;   // 0 never > any selected key
  __syncthreads();
  if (i >= n) return;
  unsigned int c = 0;
  #pragma unroll 8
  for (int j = 0; j < RANK_JT; ++j)
    c += (tile[j] > ki) ? 1u : 0u;
  if (c) atomicAdd(&rank[i], c);
}

__global__ void __launch_bounds__(256) k_scatter(const unsigned long long* __restrict__ sel,
                                                 const Hdr* __restrict__ h,
                                                 const unsigned int* __restrict__ rank,
                                                 unsigned long long* __restrict__ sel2){
  int i = blockIdx.x*256 + threadIdx.x;
  int n = (int)h->selCount; if (n > SEL_CAP) n = SEL_CAP;
  if (i >= n) return;
  unsigned int r = rank[i];
  if (r < N_TOPK) sel2[r] = sel[i];
}

// ---- gather + re-decode top-6000 ----
__global__ void k_gather(const unsigned long long* __restrict__ sel2,
                         const int* __restrict__ bidx, const int* __restrict__ isz,
                         const float* __restrict__ anc, const float* __restrict__ delta,
                         float4* __restrict__ boxes, float* __restrict__ areas,
                         int* __restrict__ bidxv, int* __restrict__ validv)
{
  int k = blockIdx.x*blockDim.x + threadIdx.x;
  if (k >= N_TOPK) return;
  unsigned long long key = sel2[k];
  unsigned int uv = (unsigned int)(key >> 32);
  int i = (int)(0xFFFFFFFFu - (unsigned int)(key & 0xFFFFFFFFull));
  float x1,y1,x2,y2; bool valid;
  decode_one(i, bidx, isz, anc, delta, x1, y1, x2, y2, valid);
  boxes[k] = make_float4(x1, y1, x2, y2);
  areas[k] = __fmul_rn(__fsub_rn(x2, x1), __fsub_rn(y2, y1));
  bidxv[k] = bidx[i];
  validv[k] = (uv >= 0x80000000u) ? 1 : 0;   // finite score
}

// ---- NMS suppression bitmask: 64x64 tiles ----
__global__ void __launch_bounds__(64) k_mask(const float4* __restrict__ boxes,
                                             const float* __restrict__ areas,
                                             unsigned long long* __restrict__ mask)
{
  __shared__ float4 cbox[64];
  __shared__ float carea[64];
  int t = threadIdx.x;
  int cb = blockIdx.x, rb = blockIdx.y;
  int col0 = cb * 64;
  int c = col0 + t;
  if (c < N_TOPK){ cbox[t] = boxes[c]; carea[t] = areas[c]; }
  __syncthreads();
  int r = rb * 64 + t;
  if (r >= N_TOPK) return;
  float4 rbx = boxes[r];
  float ra = areas[r];
  unsigned long long m = 0ULL;
  int jmax = N_TOPK - col0; if (jmax > 64) jmax = 64;
  for (int jj = 0; jj < jmax; ++jj){
    int cc = col0 + jj;
    if (cc <= r) continue;
    float4 cbx = cbox[jj];
    float ix1 = fmaxf(rbx.x, cbx.x);
    float iy1 = fmaxf(rbx.y, cbx.y);
    float ix2 = fminf(rbx.z, cbx.z);
    float iy2 = fminf(rbx.w, cbx.w);
    float iw = fmaxf(__fsub_rn(ix2, ix1), 0.0f);
    float ih = fmaxf(__fsub_rn(iy2, iy1), 0.0f);
    float inter = __fmul_rn(iw, ih);
    float denom = __fadd_rn(__fsub_rn(__fadd_rn(ra, carea[jj]), inter), 1e-9f);
    float iou = __fdiv_rn(inter, denom);
    if (iou > NMS_THRESH) m |= (1ULL << jj);
  }
  mask[(size_t)r * WORDS + cb] = m;
}

// ---- chunked greedy scan, 4 waves (256 thr) ----
__global__ void __launch_bounds__(256) k_scan(const unsigned long long* __restrict__ mask,
                                              const int* __restrict__ validv,
                                              const float4* __restrict__ boxes,
                                              const int* __restrict__ bidxv,
                                              float* __restrict__ out)
{
  const int t = threadIdx.x;
  const int lane = t & 63;
  const int wv = t >> 6;
  __shared__ unsigned long long remv[WORDS];
  __shared__ int keep[POST_K];
  for (int w = t; w < WORDS; w += 256) remv[w] = 0ULL;
  __syncthreads();

  const int NCHUNK = (N_TOPK + 63) / 64;   // 94
  int cnt = 0;
  // prefetch chunk 0 diagonal + valid
  unsigned long long dvP = (lane < N_TOPK) ? mask[(size_t)lane * WORDS + 0] : 0ULL;
  bool vbP = (lane < N_TOPK) ? (validv[lane] != 0) : false;

  for (int c = 0; c < NCHUNK; ++c){
    const int base = c * 64;
    const int nrows = (N_TOPK - base < 64) ? (N_TOPK - base) : 64;
    unsigned long long dv = (lane < nrows) ? dvP : 0ULL;
    bool vb = (lane < nrows) ? vbP : false;
    unsigned long long prevw = remv[c];
    unsigned long long vmask = __ballot(vb);
    // 64-step sequential resolve, replicated on all waves (register shfl chain)
    unsigned long long s = prevw, alive = 0ULL;
    #pragma unroll
    for (int i = 0; i < 64; ++i){
      unsigned long long d = __shfl(dv, i);
      if (((s >> i) & 1ULL) == 0ULL){
        s |= d;
        alive |= (1ULL << i);
      }
    }
    unsigned long long keepb = alive & vmask;
    if (wv == 0 && ((keepb >> lane) & 1ULL)){
      int pos = cnt + __popcll(keepb & ((1ULL << lane) - 1ULL));
      if (pos < POST_K) keep[pos] = base + lane;
    }
    cnt += (int)__popcll(keepb);
    if (cnt >= POST_K || c + 1 == NCHUNK) break;   // uniform across all threads
    // prefetch chunk c+1 diagonal + valid (overlaps with OR loads below)
    {
      int nb = base + 64;
      int nr2 = N_TOPK - nb; if (nr2 > 64) nr2 = 64;
      bool in2 = lane < nr2;
      int row2 = nb + lane;
      dvP = in2 ? mask[(size_t)row2 * WORDS + (c + 1)] : 0ULL;
      vbP = in2 ? (validv[row2] != 0) : false;
    }
    // OR phase: wave wv handles rows [wv*16, wv*16+16); lane<47 owns words 2l,2l+1
    if (lane < 47){
      unsigned long long a0 = 0ULL, a1 = 0ULL;
      const char* mb = (const char*)mask;
      const size_t lo = (size_t)lane * 16;
      #pragma unroll
      for (int i = 0; i < 16; ++i){
        int rr = base + wv*16 + i;
        unsigned long long selm = 0ULL - ((alive >> (wv*16 + i)) & 1ULL);
        ulonglong2 vv = *(const ulonglong2*)(mb + (size_t)rr * (WORDS * 8) + lo);
        a0 |= vv.x & selm;
        a1 |= vv.y & selm;
      }
      if (a0) atomicOr(&remv[2*lane],     a0);
      if (a1) atomicOr(&remv[2*lane + 1], a1);
    }
    __syncthreads();
  }
  __syncthreads();
  int kc = cnt > POST_K ? POST_K : cnt;
  for (int cc = t; cc < POST_K; cc += 256){
    float4 b; float bi;
    if (cc < kc){
      int i = keep[cc];
      b = boxes[i];
      bi = (float)bidxv[i];
    } else {
      b = make_float4(0.f, 0.f, 0.f, 0.f);
      bi = -1.0f;
    }
    out[cc*4+0] = b.x; out[cc*4+1] = b.y; out[cc*4+2] = b.z; out[cc*4+3] = b.w;
    out[POST_K*4 + cc] = bi;
  }
}

extern "C" void kernel_launch(void* const* d_in, const int* in_sizes, int n_in,
                              void* d_out, int out_size, void* d_ws, size_t ws_size,
                              hipStream_t stream)
{
  const int*   bidx   = (const int*)d_in[0];
  const int*   isz    = (const int*)d_in[1];
  const float* anc    = (const float*)d_in[2];
  const float* logits = (const float*)d_in[3];
  const float* delta  = (const float*)d_in[4];
  const int N = in_sizes[0];

  char* ws = (char*)d_ws;
  size_t off = 0;
  unsigned int* u = (unsigned int*)(ws + off);      off += (size_t)N * 4;
  off = (off + 255) & ~(size_t)255;
  Hdr* h = (Hdr*)(ws + off);                        off += sizeof(Hdr);
  off = (off + 255) & ~(size_t)255;
  unsigned long long* sel = (unsigned long long*)(ws + off); off += (size_t)SEL_CAP * 8;
  unsigned int* rank = (unsigned int*)(ws + off);   off += (size_t)SEL_CAP * 4;
  off = (off + 255) & ~(size_t)255;
  unsigned long long* sel2 = (unsigned long long*)(ws + off); off += (size_t)N_TOPK * 8;
  off = (off + 255) & ~(size_t)255;
  float4* boxes = (float4*)(ws + off);              off += (size_t)N_TOPK * 16;
  float*  areas = (float*)(ws + off);               off += (size_t)N_TOPK * 4;
  int*    bidxv = (int*)(ws + off);                 off += (size_t)N_TOPK * 4;
  int*    validv= (int*)(ws + off);                 off += (size_t)N_TOPK * 4;
  off = (off + 255) & ~(size_t)255;
  unsigned long long* mask = (unsigned long long*)(ws + off); off += (size_t)N_TOPK * WORDS * 8;
  (void)ws_size; (void)n_in; (void)out_size;

  float* out = (float*)d_out;

  hipLaunchKernelGGL(k_init,   dim3(1),    dim3(256), 0, stream, h, rank);
  hipLaunchKernelGGL(k_decode, dim3(2048), dim3(256), 0, stream, bidx, isz, anc, logits, delta, u, N, h);
  hipLaunchKernelGGL(k_pick,   dim3(1),    dim3(256), 0, stream, h);
  for (int shift = 16; shift >= 0; shift -= 8){
    hipLaunchKernelGGL(k_hist, dim3(1024), dim3(256), 0, stream, u, N, h, shift);
    hipLaunchKernelGGL(k_pick, dim3(1),    dim3(256), 0, stream, h);
  }
  hipLaunchKernelGGL(k_compact, dim3(2048), dim3(256), 0, stream, u, N, h, sel);
  hipLaunchKernelGGL(k_rank,    dim3(SEL_CAP/256, SEL_CAP/RANK_JT), dim3(256), 0, stream, sel, h, rank);
  hipLaunchKernelGGL(k_scatter, dim3(SEL_CAP/256), dim3(256), 0, stream, sel, h, rank, sel2);
  hipLaunchKernelGGL(k_gather,  dim3((N_TOPK + 255)/256), dim3(256), 0, stream,
                     sel2, bidx, isz, anc, delta, boxes, areas, bidxv, validv);
  hipLaunchKernelGGL(k_mask,    dim3(WORDS, WORDS), dim3(64), 0, stream, boxes, areas, mask);
  hipLaunchKernelGGL(k_scan,    dim3(1),    dim3(256), 0, stream, mask, validv, boxes, bidxv, out);
}

// Round 5
// 209.053 us; speedup vs baseline: 2.9025x; 1.4060x over previous
//
#include <hip/hip_runtime.h>
#include <math.h>

#define N_TOPK 6000
#define POST_K 1000
#define WORDS 94            // ceil(6000/64)
#define SEL_CAP 8192
#define RANK_JT 1024
#define NMS_THRESH 0.7f
#define HPAD 16             // one hist counter per 64B cacheline

struct Hdr {
  unsigned int hist[256*HPAD];  // padded: bin b at hist[b*HPAD]
  unsigned int prefix;     // accumulated high bits of u* (radix select)
  unsigned int kth;        // remaining rank within current prefix
  unsigned int selCount;
  unsigned int pad;
};

// ---- shared decode (must match reference numerics; _rn blocks FMA contraction) ----
__device__ __forceinline__ void decode_one(int i,
    const int* __restrict__ bidx, const int* __restrict__ isz,
    const float* __restrict__ anc, const float* __restrict__ delta,
    float& x1, float& y1, float& x2, float& y2, bool& valid)
{
  float a0 = anc[(size_t)i*4+0], a1 = anc[(size_t)i*4+1];
  float a2 = anc[(size_t)i*4+2], a3 = anc[(size_t)i*4+3];
  float aw = __fsub_rn(a2, a0);
  float ah = __fsub_rn(a3, a1);
  float ax = __fadd_rn(a0, __fmul_rn(0.5f, aw));
  float ay = __fadd_rn(a1, __fmul_rn(0.5f, ah));
  float d0 = delta[(size_t)i*4+0], d1 = delta[(size_t)i*4+1];
  float d2 = delta[(size_t)i*4+2], d3 = delta[(size_t)i*4+3];
  float px = __fadd_rn(ax, __fmul_rn(d0, aw));
  float py = __fadd_rn(ay, __fmul_rn(d1, ah));
  float c2 = fminf(fmaxf(d2, -10.0f), 10.0f);
  float c3 = fminf(fmaxf(d3, -10.0f), 10.0f);
  // correctly-rounded f32 exp via double (central w.r.t. any 1-ulp reference exp)
  float pw = __fmul_rn(aw, (float)exp((double)c2));
  float ph = __fmul_rn(ah, (float)exp((double)c3));
  int b = bidx[i];
  float H = (float)isz[b*2+0];
  float W = (float)isz[b*2+1];
  float Wm = __fsub_rn(W, 1.0f);
  float Hm = __fsub_rn(H, 1.0f);
  float hw = __fmul_rn(0.5f, pw);
  float hh = __fmul_rn(0.5f, ph);
  x1 = fminf(fmaxf(__fsub_rn(px, hw), 0.0f), Wm);
  y1 = fminf(fmaxf(__fsub_rn(py, hh), 0.0f), Hm);
  x2 = fminf(fmaxf(__fadd_rn(px, hw), 0.0f), Wm);
  y2 = fminf(fmaxf(__fadd_rn(py, hh), 0.0f), Hm);
  valid = (__fsub_rn(x2, x1) >= 16.0f) && (__fsub_rn(y2, y1) >= 16.0f);
}

// ---- stage 1: decode + score -> monotone u32 key; fused top-8-bit histogram ----
__global__ void k_decode(const int* __restrict__ bidx, const int* __restrict__ isz,
                         const float* __restrict__ anc, const float* __restrict__ logits,
                         const float* __restrict__ delta, unsigned int* __restrict__ u, int N,
                         Hdr* __restrict__ h)
{
  __shared__ unsigned int lh[256];
  lh[threadIdx.x] = 0;
  __syncthreads();
  for (int i = blockIdx.x*blockDim.x + threadIdx.x; i < N; i += gridDim.x*blockDim.x){
    float x1,y1,x2,y2; bool valid;
    decode_one(i, bidx, isz, anc, delta, x1, y1, x2, y2, valid);
    float s;
    if (valid){
      float x = logits[i];
      float e = (float)exp(-(double)x);           // exp-form sigmoid (XLA logistic expander)
      s = __fdiv_rn(1.0f, __fadd_rn(1.0f, e));
    } else {
      s = -__builtin_inff();
    }
    unsigned int b = __float_as_uint(s);
    unsigned int key = (b & 0x80000000u) ? ~b : (b | 0x80000000u);
    u[i] = key;
    atomicAdd(&lh[key >> 24], 1u);
  }
  __syncthreads();
  unsigned int c = lh[threadIdx.x];
  if (c) atomicAdd(&h->hist[threadIdx.x * HPAD], c);   // padded: line-private counters
}

// ---- radix select ----
__global__ void k_init(Hdr* h, unsigned int* rank){
  for (int i = threadIdx.x; i < 256*HPAD; i += 256) h->hist[i] = 0;
  for (int i = threadIdx.x; i < SEL_CAP; i += 256) rank[i] = 0;
  if (threadIdx.x == 0){ h->prefix = 0; h->kth = N_TOPK; h->selCount = 0; }
}

__global__ void k_hist(const unsigned int* __restrict__ u, int N, Hdr* __restrict__ h, int shift){
  __shared__ unsigned int lh[256];
  if (threadIdx.x < 256) lh[threadIdx.x] = 0;
  __syncthreads();
  unsigned int pre = h->prefix;
  for (int i = blockIdx.x*blockDim.x + threadIdx.x; i < N; i += gridDim.x*blockDim.x){
    unsigned int v = u[i];
    bool ok = ((v >> (shift + 8)) == pre);
    if (ok) atomicAdd(&lh[(v >> shift) & 255u], 1u);
  }
  __syncthreads();
  if (threadIdx.x < 256){
    unsigned int c = lh[threadIdx.x];
    if (c) atomicAdd(&h->hist[threadIdx.x * HPAD], c);
  }
}

// ---- wave-parallel pick: 64 lanes x 4 bins, suffix-scan + ballot ----
__global__ void __launch_bounds__(64) k_pick(Hdr* h){
  const int t = threadIdx.x;
  unsigned int c0 = h->hist[(4*t+0)*HPAD];
  unsigned int c1 = h->hist[(4*t+1)*HPAD];
  unsigned int c2 = h->hist[(4*t+2)*HPAD];
  unsigned int c3 = h->hist[(4*t+3)*HPAD];
  // reset for next pass
  h->hist[(4*t+0)*HPAD] = 0; h->hist[(4*t+1)*HPAD] = 0;
  h->hist[(4*t+2)*HPAD] = 0; h->hist[(4*t+3)*HPAD] = 0;
  unsigned int local = c0 + c1 + c2 + c3;
  // inclusive suffix sum across lanes: suf_t = sum_{j>=t} local_j
  unsigned int suf = local;
  #pragma unroll
  for (int d = 1; d < 64; d <<= 1){
    unsigned int o = __shfl_down(suf, d);
    if (t + d < 64) suf += o;
  }
  unsigned int k = h->kth;
  unsigned int exc = suf - local;          // sum over lanes > t
  unsigned int s3 = exc + c3;              // inclusive suffix at bin 4t+3
  unsigned int s2 = s3 + c2;
  unsigned int s1 = s2 + c1;
  unsigned int s0 = s1 + c0;               // inclusive suffix at bin 4t
  int bb = -1; unsigned int newk = 0;
  if (s3 >= k){ bb = 4*t+3; newk = k - (s3 - c3); }
  else if (s2 >= k){ bb = 4*t+2; newk = k - (s2 - c2); }
  else if (s1 >= k){ bb = 4*t+1; newk = k - (s1 - c1); }
  else if (s0 >= k){ bb = 4*t+0; newk = k - (s0 - c0); }
  unsigned long long q = __ballot(s0 >= k);
  int hi = 63 - __clzll(q);                // highest lane with a qualifying bin
  if (t == hi){
    h->prefix = (h->prefix << 8) | (unsigned int)bb;
    h->kth = newk;
  }
}

// ---- compact all u >= u*: block-aggregated allocation (1 global atomic/block).
//  Slot order is irrelevant — k_rank orders by key afterwards. ----
__global__ void __launch_bounds__(256) k_compact(const unsigned int* __restrict__ u, int N,
                                                 Hdr* __restrict__ h, unsigned long long* __restrict__ sel){
  __shared__ unsigned long long lbuf[1024];
  __shared__ unsigned int lcnt, lbase;
  if (threadIdx.x == 0) lcnt = 0;
  __syncthreads();
  unsigned int ustar = h->prefix;
  for (int i = blockIdx.x*blockDim.x + threadIdx.x; i < N; i += gridDim.x*blockDim.x){
    unsigned int v = u[i];
    if (v >= ustar){
      unsigned long long key = ((unsigned long long)v << 32)
                             | (unsigned long long)(0xFFFFFFFFu - (unsigned int)i);
      unsigned int p = atomicAdd(&lcnt, 1u);
      if (p < 1024){
        lbuf[p] = key;
      } else {                               // overflow fallback (statistically never)
        unsigned int gp = atomicAdd(&h->selCount, 1u);
        if (gp < SEL_CAP) sel[gp] = key;
      }
    }
  }
  __syncthreads();
  unsigned int n = lcnt; if (n > 1024) n = 1024;
  if (threadIdx.x == 0 && n) lbase = atomicAdd(&h->selCount, n);
  __syncthreads();
  if (n){
    unsigned int base = lbase;
    for (unsigned int kk = threadIdx.x; kk < n; kk += 256){
      unsigned int p = base + kk;
      if (p < SEL_CAP) sel[p] = lbuf[kk];
    }
  }
}

// ---- rank instead of sort: rank_i = #{j : key_j > key_i} (keys unique). ----
__global__ void __launch_bounds__(256) k_rank(const unsigned long long* __restrict__ sel,
                                              const Hdr* __restrict__ h,
                                              unsigned int* __restrict__ rank){
  __shared__ unsigned long long tile[RANK_JT];
  int n = (int)h->selCount; if (n > SEL_CAP) n = SEL_CAP;
  int i = blockIdx.x*256 + threadIdx.x;
  unsigned long long ki = (i < n) ? sel[i] : 0ULL;
  int j0 = blockIdx.y * RANK_JT;
  for (int jj = threadIdx.x; jj < RANK_JT; jj += 256)
    tile[jj] = (j0 + jj < n) ? sel[j0 + jj] : 0ULL;   // 0 never > any selected key
  __syncthreads();
  if (i >= n) return;
  unsigned int c = 0;
  #pragma unroll 8
  for (int j = 0; j < RANK_JT; ++j)
    c += (tile[j] > ki) ? 1u : 0u;
  if (c) atomicAdd(&rank[i], c);
}

__global__ void __launch_bounds__(256) k_scatter(const unsigned long long* __restrict__ sel,
                                                 const Hdr* __restrict__ h,
                                                 const unsigned int* __restrict__ rank,
                                                 unsigned long long* __restrict__ sel2){
  int i = blockIdx.x*256 + threadIdx.x;
  int n = (int)h->selCount; if (n > SEL_CAP) n = SEL_CAP;
  if (i >= n) return;
  unsigned int r = rank[i];
  if (r < N_TOPK) sel2[r] = sel[i];
}

// ---- gather + re-decode top-6000 ----
__global__ void k_gather(const unsigned long long* __restrict__ sel2,
                         const int* __restrict__ bidx, const int* __restrict__ isz,
                         const float* __restrict__ anc, const float* __restrict__ delta,
                         float4* __restrict__ boxes, float* __restrict__ areas,
                         int* __restrict__ bidxv, int* __restrict__ validv)
{
  int k = blockIdx.x*blockDim.x + threadIdx.x;
  if (k >= N_TOPK) return;
  unsigned long long key = sel2[k];
  unsigned int uv = (unsigned int)(key >> 32);
  int i = (int)(0xFFFFFFFFu - (unsigned int)(key & 0xFFFFFFFFull));
  float x1,y1,x2,y2; bool valid;
  decode_one(i, bidx, isz, anc, delta, x1, y1, x2, y2, valid);
  boxes[k] = make_float4(x1, y1, x2, y2);
  areas[k] = __fmul_rn(__fsub_rn(x2, x1), __fsub_rn(y2, y1));
  bidxv[k] = bidx[i];
  validv[k] = (uv >= 0x80000000u) ? 1 : 0;   // finite score
}

// ---- NMS suppression bitmask: 64x64 tiles ----
__global__ void __launch_bounds__(64) k_mask(const float4* __restrict__ boxes,
                                             const float* __restrict__ areas,
                                             unsigned long long* __restrict__ mask)
{
  __shared__ float4 cbox[64];
  __shared__ float carea[64];
  int t = threadIdx.x;
  int cb = blockIdx.x, rb = blockIdx.y;
  int col0 = cb * 64;
  int c = col0 + t;
  if (c < N_TOPK){ cbox[t] = boxes[c]; carea[t] = areas[c]; }
  __syncthreads();
  int r = rb * 64 + t;
  if (r >= N_TOPK) return;
  float4 rbx = boxes[r];
  float ra = areas[r];
  unsigned long long m = 0ULL;
  int jmax = N_TOPK - col0; if (jmax > 64) jmax = 64;
  for (int jj = 0; jj < jmax; ++jj){
    int cc = col0 + jj;
    if (cc <= r) continue;
    float4 cbx = cbox[jj];
    float ix1 = fmaxf(rbx.x, cbx.x);
    float iy1 = fmaxf(rbx.y, cbx.y);
    float ix2 = fminf(rbx.z, cbx.z);
    float iy2 = fminf(rbx.w, cbx.w);
    float iw = fmaxf(__fsub_rn(ix2, ix1), 0.0f);
    float ih = fmaxf(__fsub_rn(iy2, iy1), 0.0f);
    float inter = __fmul_rn(iw, ih);
    float denom = __fadd_rn(__fsub_rn(__fadd_rn(ra, carea[jj]), inter), 1e-9f);
    float iou = __fdiv_rn(inter, denom);
    if (iou > NMS_THRESH) m |= (1ULL << jj);
  }
  mask[(size_t)r * WORDS + cb] = m;
}

// ---- chunked greedy scan, 4 waves (256 thr) ----
__global__ void __launch_bounds__(256) k_scan(const unsigned long long* __restrict__ mask,
                                              const int* __restrict__ validv,
                                              const float4* __restrict__ boxes,
                                              const int* __restrict__ bidxv,
                                              float* __restrict__ out)
{
  const int t = threadIdx.x;
  const int lane = t & 63;
  const int wv = t >> 6;
  __shared__ unsigned long long remv[WORDS];
  __shared__ int keep[POST_K];
  for (int w = t; w < WORDS; w += 256) remv[w] = 0ULL;
  __syncthreads();

  const int NCHUNK = (N_TOPK + 63) / 64;   // 94
  int cnt = 0;
  // prefetch chunk 0 diagonal + valid
  unsigned long long dvP = (lane < N_TOPK) ? mask[(size_t)lane * WORDS + 0] : 0ULL;
  bool vbP = (lane < N_TOPK) ? (validv[lane] != 0) : false;

  for (int c = 0; c < NCHUNK; ++c){
    const int base = c * 64;
    const int nrows = (N_TOPK - base < 64) ? (N_TOPK - base) : 64;
    unsigned long long dv = (lane < nrows) ? dvP : 0ULL;
    bool vb = (lane < nrows) ? vbP : false;
    unsigned long long prevw = remv[c];
    unsigned long long vmask = __ballot(vb);
    // 64-step sequential resolve, replicated on all waves (register shfl chain)
    unsigned long long s = prevw, alive = 0ULL;
    #pragma unroll
    for (int i = 0; i < 64; ++i){
      unsigned long long d = __shfl(dv, i);
      if (((s >> i) & 1ULL) == 0ULL){
        s |= d;
        alive |= (1ULL << i);
      }
    }
    unsigned long long keepb = alive & vmask;
    if (wv == 0 && ((keepb >> lane) & 1ULL)){
      int pos = cnt + __popcll(keepb & ((1ULL << lane) - 1ULL));
      if (pos < POST_K) keep[pos] = base + lane;
    }
    cnt += (int)__popcll(keepb);
    if (cnt >= POST_K || c + 1 == NCHUNK) break;   // uniform across all threads
    // prefetch chunk c+1 diagonal + valid (overlaps with OR loads below)
    {
      int nb = base + 64;
      int nr2 = N_TOPK - nb; if (nr2 > 64) nr2 = 64;
      bool in2 = lane < nr2;
      int row2 = nb + lane;
      dvP = in2 ? mask[(size_t)row2 * WORDS + (c + 1)] : 0ULL;
      vbP = in2 ? (validv[row2] != 0) : false;
    }
    // OR phase: wave wv handles rows [wv*16, wv*16+16); lane<47 owns words 2l,2l+1
    if (lane < 47){
      unsigned long long a0 = 0ULL, a1 = 0ULL;
      const char* mb = (const char*)mask;
      const size_t lo = (size_t)lane * 16;
      #pragma unroll
      for (int i = 0; i < 16; ++i){
        int rr = base + wv*16 + i;
        unsigned long long selm = 0ULL - ((alive >> (wv*16 + i)) & 1ULL);
        ulonglong2 vv = *(const ulonglong2*)(mb + (size_t)rr * (WORDS * 8) + lo);
        a0 |= vv.x & selm;
        a1 |= vv.y & selm;
      }
      if (a0) atomicOr(&remv[2*lane],     a0);
      if (a1) atomicOr(&remv[2*lane + 1], a1);
    }
    __syncthreads();
  }
  __syncthreads();
  int kc = cnt > POST_K ? POST_K : cnt;
  for (int cc = t; cc < POST_K; cc += 256){
    float4 b; float bi;
    if (cc < kc){
      int i = keep[cc];
      b = boxes[i];
      bi = (float)bidxv[i];
    } else {
      b = make_float4(0.f, 0.f, 0.f, 0.f);
      bi = -1.0f;
    }
    out[cc*4+0] = b.x; out[cc*4+1] = b.y; out[cc*4+2] = b.z; out[cc*4+3] = b.w;
    out[POST_K*4 + cc] = bi;
  }
}

extern "C" void kernel_launch(void* const* d_in, const int* in_sizes, int n_in,
                              void* d_out, int out_size, void* d_ws, size_t ws_size,
                              hipStream_t stream)
{
  const int*   bidx   = (const int*)d_in[0];
  const int*   isz    = (const int*)d_in[1];
  const float* anc    = (const float*)d_in[2];
  const float* logits = (const float*)d_in[3];
  const float* delta  = (const float*)d_in[4];
  const int N = in_sizes[0];

  char* ws = (char*)d_ws;
  size_t off = 0;
  unsigned int* u = (unsigned int*)(ws + off);      off += (size_t)N * 4;
  off = (off + 255) & ~(size_t)255;
  Hdr* h = (Hdr*)(ws + off);                        off += sizeof(Hdr);
  off = (off + 255) & ~(size_t)255;
  unsigned long long* sel = (unsigned long long*)(ws + off); off += (size_t)SEL_CAP * 8;
  unsigned int* rank = (unsigned int*)(ws + off);   off += (size_t)SEL_CAP * 4;
  off = (off + 255) & ~(size_t)255;
  unsigned long long* sel2 = (unsigned long long*)(ws + off); off += (size_t)N_TOPK * 8;
  off = (off + 255) & ~(size_t)255;
  float4* boxes = (float4*)(ws + off);              off += (size_t)N_TOPK * 16;
  float*  areas = (float*)(ws + off);               off += (size_t)N_TOPK * 4;
  int*    bidxv = (int*)(ws + off);                 off += (size_t)N_TOPK * 4;
  int*    validv= (int*)(ws + off);                 off += (size_t)N_TOPK * 4;
  off = (off + 255) & ~(size_t)255;
  unsigned long long* mask = (unsigned long long*)(ws + off); off += (size_t)N_TOPK * WORDS * 8;
  (void)ws_size; (void)n_in; (void)out_size;

  float* out = (float*)d_out;

  hipLaunchKernelGGL(k_init,   dim3(1),    dim3(256), 0, stream, h, rank);
  hipLaunchKernelGGL(k_decode, dim3(2048), dim3(256), 0, stream, bidx, isz, anc, logits, delta, u, N, h);
  hipLaunchKernelGGL(k_pick,   dim3(1),    dim3(64),  0, stream, h);
  for (int shift = 16; shift >= 0; shift -= 8){
    hipLaunchKernelGGL(k_hist, dim3(1024), dim3(256), 0, stream, u, N, h, shift);
    hipLaunchKernelGGL(k_pick, dim3(1),    dim3(64),  0, stream, h);
  }
  hipLaunchKernelGGL(k_compact, dim3(512),  dim3(256), 0, stream, u, N, h, sel);
  hipLaunchKernelGGL(k_rank,    dim3(SEL_CAP/256, SEL_CAP/RANK_JT), dim3(256), 0, stream, sel, h, rank);
  hipLaunchKernelGGL(k_scatter, dim3(SEL_CAP/256), dim3(256), 0, stream, sel, h, rank, sel2);
  hipLaunchKernelGGL(k_gather,  dim3((N_TOPK + 255)/256), dim3(256), 0, stream,
                     sel2, bidx, isz, anc, delta, boxes, areas, bidxv, validv);
  hipLaunchKernelGGL(k_mask,    dim3(WORDS, WORDS), dim3(64), 0, stream, boxes, areas, mask);
  hipLaunchKernelGGL(k_scan,    dim3(1),    dim3(256), 0, stream, mask, validv, boxes, bidxv, out);
}